// Round 9
// baseline (1800.190 us; speedup 1.0000x reference)
//
#include <hip/hip_runtime.h>
#include <stdint.h>

// Problem constants
#define HID 100
#define B_TOTAL 512
#define T_IN 1000
#define NB 2
#define BLOCK 512   // 8 waves, 2 waves/SIMD
#define RSTR 160    // f16 row stride (320 B): batch 1 lands 16 banks away

typedef __fp16 f16x8 __attribute__((ext_vector_type(8)));
typedef float f32x4 __attribute__((ext_vector_type(4)));

#define MF(A, B, C) __builtin_amdgcn_mfma_f32_16x16x32_f16((A), (B), (C), 0, 0, 0)
#define Z4 ((f32x4){0.f, 0.f, 0.f, 0.f})

// ---- fast activation math (verified: absmax unchanged) ----
#if __has_builtin(__builtin_amdgcn_exp2f)
#define EXP2F(x) __builtin_amdgcn_exp2f(x)
#else
#define EXP2F(x) exp2f(x)
#endif
#if __has_builtin(__builtin_amdgcn_rcpf)
#define RCPF(x) __builtin_amdgcn_rcpf(x)
#else
#define RCPF(x) (1.0f / (x))
#endif
#define LOG2E 1.44269504f
__device__ __forceinline__ float sigm(float x) { return RCPF(1.0f + EXP2F(-LOG2E * x)); }
__device__ __forceinline__ float tanh_fast(float x) {
  return 1.0f - 2.0f * RCPF(EXP2F((2.0f * LOG2E) * x) + 1.0f);
}

// Gate-interleaved row permutation (R1+-verified): frag row m of N-tile tl holds
// original gate row g*100 + (4*tl + q), g = m&3, q = m>>2.
// => D: lane holds gates (i,f,g,o) of k=4*tl+(lane>>4), batch lane&1 in regs 0..3.
__device__ __forceinline__ int jmap(int tl, int m) { return (m & 3) * 100 + 4 * tl + (m >> 2); }

// weight element fetchers over padded K layouts (0 in pad regions).
// Bias fused at K=101 (hi) / 102 (lo) against B=1.0 — f32-exact via hi/lo f16 pair.
// L1 K-layout: [0..99]=h1, [100]=x, [101]=b_hi, [102]=b_lo, [103..127]=0
__device__ __forceinline__ __fp16 w1e(const float* Whh1, const float* Wih1,
                                      const float* bih1, const float* bhh1, int j, int k) {
  if (k < 100) return (__fp16)Whh1[j * 100 + k];
  if (k == 100) return (__fp16)Wih1[j];
  if (k == 101 || k == 102) {
    float b = bih1[j] + bhh1[j];
    __fp16 hi = (__fp16)b;
    return (k == 101) ? hi : (__fp16)(b - (float)hi);
  }
  return (__fp16)0.0f;
}
// L2 K-layout: [0..99]=h1(t), [100]=0(x-slot junk), [101]=b_hi, [102]=b_lo,
//              [103..111]=0, [112..211]=h2(t-1), [212..223]=0
__device__ __forceinline__ __fp16 w2e(const float* Wih2, const float* Whh2,
                                      const float* bih2, const float* bhh2, int j, int k) {
  if (k < 100) return (__fp16)Wih2[j * 100 + k];
  if (k == 101 || k == 102) {
    float b = bih2[j] + bhh2[j];
    __fp16 hi = (__fp16)b;
    return (k == 101) ? hi : (__fp16)(b - (float)hi);
  }
  if (k >= 112 && k < 212) return (__fp16)Whh2[j * 100 + (k - 112)];
  return (__fp16)0.0f;
}

// A-operand fragment builders: lane row m=lane&15, K elems (lane>>4)*8+0..7 of K-tile kt
__device__ __forceinline__ f16x8 mka1(const float* Whh1, const float* Wih1,
                                      const float* bih1, const float* bhh1,
                                      int tl, int kt, int m, int kg) {
  int j = jmap(tl, m);
  f16x8 r;
#pragma unroll
  for (int e = 0; e < 8; e++) r[e] = w1e(Whh1, Wih1, bih1, bhh1, j, kt * 32 + kg * 8 + e);
  return r;
}
__device__ __forceinline__ f16x8 mka2(const float* Wih2, const float* Whh2,
                                      const float* bih2, const float* bhh2,
                                      int tl, int kt, int m, int kg) {
  int j = jmap(tl, m);
  f16x8 r;
#pragma unroll
  for (int e = 0; e < 8; e++) r[e] = w2e(Wih2, Whh2, bih2, bhh2, j, kt * 32 + kg * 8 + e);
  return r;
}

// Wave roles (specialized to fit registers; union'd frag array Wf[42]):
//   wv 0..3 = L1 waves: tiles {wv, 4+wv, ..., 20+wv}; wv0 += tile24-L1; wv3 += tile24-L2
//   wv 4..7 = L2 waves: tiles {wv-4, 4+(wv-4), ..., 20+(wv-4)}
__global__ __launch_bounds__(BLOCK, 2) void lstm2_mfma(
    const float* __restrict__ input,  // [512,1000]
    const float* __restrict__ Wih1,   // [400,1]
    const float* __restrict__ Whh1,   // [400,100]
    const float* __restrict__ bih1,
    const float* __restrict__ bhh1,
    const float* __restrict__ Wih2,   // [400,100]
    const float* __restrict__ Whh2,   // [400,100]
    const float* __restrict__ bih2,
    const float* __restrict__ bhh2,
    const float* __restrict__ Wlin,   // [1,100]
    const float* __restrict__ blin,   // [1]
    const int* __restrict__ futp,
    float* __restrict__ out)          // [512, 1000+future]
{
  // parity double-buffered activation vectors (B-operand sources)
  __shared__ __align__(16) __fp16 H1X[2][NB][RSTR];   // h1 | x@100 | 1.0@101,102 | 0
  __shared__ __align__(16) __fp16 H2s[2][NB][RSTR];   // h2 | 0 pads
  __shared__ __align__(16) float  xrow[NB][T_IN];     // staged inputs (8 KB)
  __shared__ __align__(16) float  partials[2][NB][8]; // [parity][batch][slot0..4] Wlin.h2 partials

  const int tid = threadIdx.x;
  const int lane = tid & 63;
  const int wv = tid >> 6;
  const int b0 = blockIdx.x * NB;
  const int F = futp[0];
  const int TT = T_IN + F;

  // ---------------- init: stage + zero ----------------
  for (int i = tid; i < NB * T_IN; i += BLOCK) {
    int b = i / T_IN, tt = i % T_IN;
    xrow[b][tt] = input[(size_t)(b0 + b) * T_IN + tt];
  }
  if (tid < 320) { ((uint32_t*)H1X)[tid] = 0u; ((uint32_t*)H2s)[tid] = 0u; }
  if (tid < 32) ((float*)partials)[tid] = 0.0f;

  const int n15 = lane & 15;
  const int kg = lane >> 4;         // K-chunk index 0..3
  const int bcol = lane & 1;        // batch for B-reads

  // ---- per-lane act duty (each lane does at most ONE activation/step) ----
  const int sel = lane & 15;
  const int cg  = sel >> 1;         // tile slot 0..7
  const int ab  = sel & 1;          // batch
  const int aq  = lane >> 4;        // q 0..3
  bool d1 = false, d2 = false;
  int ak = 0;
  if (wv < 4) {
    if (sel < 12)                { d1 = true; ak = 4 * (4 * cg + wv) + aq; }
    else if (sel < 14 && wv == 0){ d1 = true; ak = 96 + aq; }   // tile24-L1 act
    else if (sel < 14 && wv == 3){ d2 = true; ak = 96 + aq; }   // tile24-L2 act
  } else {
    if (sel < 12)                { d2 = true; ak = 4 * (4 * cg + (wv - 4)) + aq; }
  }
  float cv = 0.0f;                  // the lane's single cell state (c1 or c2)
  const float blin0 = blin[0];
  const float wlsv = d2 ? Wlin[ak] : 0.0f;
  const int wslot = (wv == 3) ? 4 : (wv - 4);  // partials slot (valid for wv>=3)

  // ---- union'd register-resident weight fragments: 42 frags = 168 regs static ----
  f16x8 Wf[42];
  if (wv < 4) {
#pragma unroll
    for (int j = 0; j < 6; j++)
#pragma unroll
      for (int kt = 0; kt < 4; kt++)
        Wf[j * 4 + kt] = mka1(Whh1, Wih1, bih1, bhh1, 4 * j + wv, kt, n15, kg);
    if (wv == 0) {
#pragma unroll
      for (int kt = 0; kt < 4; kt++) Wf[24 + kt] = mka1(Whh1, Wih1, bih1, bhh1, 24, kt, n15, kg);
    }
    if (wv == 3) {
#pragma unroll
      for (int kt = 0; kt < 7; kt++) Wf[24 + kt] = mka2(Wih2, Whh2, bih2, bhh2, 24, kt, n15, kg);
    }
  } else {
#pragma unroll
    for (int j = 0; j < 6; j++)
#pragma unroll
      for (int kt = 0; kt < 7; kt++)
        Wf[j * 7 + kt] = mka2(Wih2, Whh2, bih2, bhh2, 4 * j + (wv - 4), kt, n15, kg);
  }

  __syncthreads();
  // specials: bias-ones at K=101,102 (both parities/batches); x(0) into parity 1
  if (tid < 4) { H1X[tid >> 1][tid & 1][101] = (__fp16)1.0f; H1X[tid >> 1][tid & 1][102] = (__fp16)1.0f; }
  if (tid >= 4 && tid < 6) H1X[1][tid - 4][100] = (__fp16)xrow[tid - 4][0];
  __syncthreads();

  f16x8 bH1a[4], bH2[3], bl2m;
  f32x4 acc[7];
  const f32x4 zz = Z4;

// ---- B-operand reads ----
#define RD_H1A(P) { _Pragma("unroll") for (int kt_ = 0; kt_ < 4; kt_++) \
    bH1a[kt_] = *(const f16x8*)&H1X[P][bcol][kt_ * 32 + kg * 8]; }
#define RD_L2M(P) { f16x8 hm_ = *(const f16x8*)&H2s[P][bcol][(kg >= 2) ? ((kg - 2) * 8) : 0]; \
    bl2m = (kg >= 2) ? hm_ : bH1a[3]; }
#define RD_H2P(P) { _Pragma("unroll") for (int kt_ = 0; kt_ < 3; kt_++) \
    bH2[kt_] = *(const f16x8*)&H2s[P][bcol][16 + kt_ * 32 + kg * 8]; }

// ---- MFMA bursts (bias arrives via K=101/102) ----
#define MFMA_L2_BODY { _Pragma("unroll") for (int j = 0; j < 6; j++) { f32x4 a_ = zz; \
    a_ = MF(Wf[j*7+0], bH1a[0], a_); a_ = MF(Wf[j*7+1], bH1a[1], a_); a_ = MF(Wf[j*7+2], bH1a[2], a_); \
    a_ = MF(Wf[j*7+3], bl2m, a_); \
    a_ = MF(Wf[j*7+4], bH2[0], a_); a_ = MF(Wf[j*7+5], bH2[1], a_); a_ = MF(Wf[j*7+6], bH2[2], a_); \
    acc[j] = a_; } }

#define MFMA_T24L2 { f32x4 a_ = zz; \
    a_ = MF(Wf[24], bH1a[0], a_); a_ = MF(Wf[25], bH1a[1], a_); a_ = MF(Wf[26], bH1a[2], a_); \
    a_ = MF(Wf[27], bl2m, a_); \
    a_ = MF(Wf[28], bH2[0], a_); a_ = MF(Wf[29], bH2[1], a_); a_ = MF(Wf[30], bH2[2], a_); \
    acc[6] = a_; }

#define MFMA_L1_BODY { _Pragma("unroll") for (int j = 0; j < 6; j++) { f32x4 a_ = zz; \
    a_ = MF(Wf[j*4+0], bH1a[0], a_); a_ = MF(Wf[j*4+1], bH1a[1], a_); \
    a_ = MF(Wf[j*4+2], bH1a[2], a_); a_ = MF(Wf[j*4+3], bH1a[3], a_); \
    acc[j] = a_; } }

#define MFMA_T24L1 { f32x4 a_ = zz; \
    a_ = MF(Wf[24], bH1a[0], a_); a_ = MF(Wf[25], bH1a[1], a_); \
    a_ = MF(Wf[26], bH1a[2], a_); a_ = MF(Wf[27], bH1a[3], a_); \
    acc[6] = a_; }

#define QSEL (cg==0?acc[0]:cg==1?acc[1]:cg==2?acc[2]:cg==3?acc[3]:cg==4?acc[4]:cg==5?acc[5]:acc[6])

// ---- ACT2 + per-wave y-partial (executed by waves >=3; d2 guards the act) ----
#define ACT2_SPEC(W_, P_) { \
    float pc_ = 0.0f; \
    if (d2) { f32x4 qq = QSEL; \
      float sf_ = sigm(qq[1]), si_ = sigm(qq[0]), tg_ = tanh_fast(qq[2]); \
      cv = sf_ * cv + si_ * tg_; \
      float h_ = sigm(qq[3]) * tanh_fast(cv); \
      H2s[W_][ab][ak] = (__fp16)h_; \
      pc_ = h_ * wlsv; } \
    pc_ += __shfl_xor(pc_, 2, 64);  pc_ += __shfl_xor(pc_, 4, 64); \
    pc_ += __shfl_xor(pc_, 8, 64);  pc_ += __shfl_xor(pc_, 16, 64); \
    pc_ += __shfl_xor(pc_, 32, 64); \
    if (lane < 2) partials[P_][lane][wslot] = pc_; }

// ---- ACT1 (TF) ----
#define ACT1_SPEC(W_) { if (d1) { f32x4 qq = QSEL; \
    float sf_ = sigm(qq[1]), si_ = sigm(qq[0]), tg_ = tanh_fast(qq[2]); \
    cv = sf_ * cv + si_ * tg_; \
    float h_ = sigm(qq[3]) * tanh_fast(cv); \
    H1X[W_][ab][ak] = (__fp16)h_; } }

// y(tt) from partials[PP_]: wave 1, 2 lanes, 2 LDS reads + store
#define YOUT(tt, PP_) { if (wv == 1 && lane < 2) { \
    const f32x4 pv_ = *(const f32x4*)&partials[PP_][lane][0]; \
    float y_ = (pv_[0] + pv_[1]) + (pv_[2] + pv_[3]) + partials[PP_][lane][4] + blin0; \
    out[(size_t)(b0 + lane) * TT + (tt)] = y_; } }

  // ---------------- prologue: L1 gates(0) from parity 1 (zeros + x(0)) ----------------
  RD_H1A(1)
  if (wv < 4) { MFMA_L1_BODY }
  if (wv == 0) { MFMA_T24L1 }
  ACT1_SPEC(0)                                         // h1(0) -> H1X[0]
  if (wv == 2 && lane < 2) H1X[0][lane][100] = (__fp16)xrow[lane][1];  // x(1)
  __syncthreads();

  // ====== teacher-forced fused: iter t does L2(t) + L1(t+1); ONE barrier/step ======
  for (int t = 0; t < T_IN - 1; t++) {
    const int p = t & 1, w = p ^ 1;
    RD_H1A(p)
    if (wv >= 3) { RD_L2M(p) RD_H2P(p) }
    if (wv >= 4) { MFMA_L2_BODY }
    if (wv == 3) { MFMA_T24L2 }
    if (wv < 4)  { MFMA_L1_BODY }
    if (wv == 0) { MFMA_T24L1 }
    if (t > 0) YOUT(t - 1, w)                          // y(t-1) from partials written last iter
    if (wv == 2 && lane < 2 && t + 2 < T_IN)
      H1X[w][lane][100] = (__fp16)xrow[lane][t + 2];   // x(t+2)
    if (wv >= 3) ACT2_SPEC(w, p)                       // h2(t) + partials(t)
    if (wv < 4)  ACT1_SPEC(w)                          // h1(t+1)
    __syncthreads();
  }

  // ---- one-time AR patches (per-wave registers; no barrier needed) ----
  if (wv < 4 && kg == 0) {                             // zero x-coeff (k=100) in L1 kt3 frags
#pragma unroll
    for (int j = 0; j < 6; j++) Wf[j * 4 + 3][4] = (__fp16)0.f;
    if (wv == 0) Wf[27][4] = (__fp16)0.f;
  }
  f32x4 wih1q = Z4;                                    // AR-only live range
  if (wv < 4) {
#pragma unroll
    for (int g = 0; g < 4; g++) wih1q[g] = Wih1[g * 100 + ak];
  }

  // ====== autoregressive: 2 barriers/step; y via f32 partials ======
  for (int t = T_IN - 1; t < TT; t++) {
    const int p = t & 1, w = p ^ 1;
    RD_H1A(p)
    if (wv >= 3) { RD_L2M(p) RD_H2P(p) }
    if (wv >= 4) { MFMA_L2_BODY }
    if (wv == 3) { MFMA_T24L2 }
    if (t == T_IN - 1) YOUT(t - 1, w)                  // catch-up y(T_IN-2)
    if (wv >= 3) ACT2_SPEC(w, p)                       // h2(t) + partials(t)
    if (wv < 4)  { MFMA_L1_BODY }
    if (wv == 0) { MFMA_T24L1 }
    __syncthreads();                                   // B1: h2(t) + partials[p] visible
    if (wv < 4) {
      const f32x4 pv_ = *(const f32x4*)&partials[p][ab][0];
      const float yv = (pv_[0] + pv_[1]) + (pv_[2] + pv_[3]) + partials[p][ab][4] + blin0;
      if (wv == 1 && lane < 2) out[(size_t)(b0 + lane) * TT + t] = yv;
      if (d1) {                                        // ACT1_AR: x-term folded in-register
        f32x4 qq = QSEL;
        qq[0] = fmaf(wih1q[0], yv, qq[0]); qq[1] = fmaf(wih1q[1], yv, qq[1]);
        qq[2] = fmaf(wih1q[2], yv, qq[2]); qq[3] = fmaf(wih1q[3], yv, qq[3]);
        float sf_ = sigm(qq[1]), si_ = sigm(qq[0]), tg_ = tanh_fast(qq[2]);
        cv = sf_ * cv + si_ * tg_;
        float h_ = sigm(qq[3]) * tanh_fast(cv);
        H1X[w][ab][ak] = (__fp16)h_;
      }
    }
    __syncthreads();                                   // B2: h1(t+1) visible
  }
}

extern "C" void kernel_launch(void* const* d_in, const int* in_sizes, int n_in,
                              void* d_out, int out_size, void* d_ws, size_t ws_size,
                              hipStream_t stream) {
  const float* input = (const float*)d_in[0];
  const float* Wih1  = (const float*)d_in[1];
  const float* Whh1  = (const float*)d_in[2];
  const float* bih1  = (const float*)d_in[3];
  const float* bhh1  = (const float*)d_in[4];
  const float* Wih2  = (const float*)d_in[5];
  const float* Whh2  = (const float*)d_in[6];
  const float* bih2  = (const float*)d_in[7];
  const float* bhh2  = (const float*)d_in[8];
  const float* Wlin  = (const float*)d_in[9];
  const float* blin  = (const float*)d_in[10];
  const int*   futp  = (const int*)d_in[11];
  float* out = (float*)d_out;

  dim3 grid(B_TOTAL / NB);  // 256 blocks, 1 per CU
  dim3 block(BLOCK);
  hipLaunchKernelGGL(lstm2_mfma, grid, block, 0, stream,
                     input, Wih1, Whh1, bih1, bhh1, Wih2, Whh2, bih2, bhh2,
                     Wlin, blin, futp, out);
}

// Round 10
// 1523.960 us; speedup vs baseline: 1.1813x; 1.1813x over previous
//
#include <hip/hip_runtime.h>
#include <stdint.h>

// Problem constants
#define HID 100
#define B_TOTAL 512
#define T_IN 1000
#define NB 2
#define BLOCK 512   // 8 waves, 2 waves/SIMD (R4/R7 optimum)
#define RSTR 160    // f16 row stride (320 B): batch 1 lands 16 banks away

typedef __fp16 f16x8 __attribute__((ext_vector_type(8)));
typedef __fp16 f16x2 __attribute__((ext_vector_type(2)));
typedef float f32x4 __attribute__((ext_vector_type(4)));

#define MF(A, B, C) __builtin_amdgcn_mfma_f32_16x16x32_f16((A), (B), (C), 0, 0, 0)
#define Z4 ((f32x4){0.f, 0.f, 0.f, 0.f})
#define ZH8 ((f16x8){(__fp16)0.f,(__fp16)0.f,(__fp16)0.f,(__fp16)0.f,(__fp16)0.f,(__fp16)0.f,(__fp16)0.f,(__fp16)0.f})

// ---- fast activation math (verified: absmax unchanged) ----
#if __has_builtin(__builtin_amdgcn_exp2f)
#define EXP2F(x) __builtin_amdgcn_exp2f(x)
#else
#define EXP2F(x) exp2f(x)
#endif
#if __has_builtin(__builtin_amdgcn_rcpf)
#define RCPF(x) __builtin_amdgcn_rcpf(x)
#else
#define RCPF(x) (1.0f / (x))
#endif
#define LOG2E 1.44269504f
__device__ __forceinline__ float sigm(float x) { return RCPF(1.0f + EXP2F(-LOG2E * x)); }
__device__ __forceinline__ float tanh_fast(float x) {
  return 1.0f - 2.0f * RCPF(EXP2F((2.0f * LOG2E) * x) + 1.0f);
}

// 8-wide f16 dot accumulating into f32 (v_dot2_f32_f16 when available)
__device__ __forceinline__ float dot8(f16x8 a, f16x8 b, float acc) {
#if __has_builtin(__builtin_amdgcn_fdot2)
#pragma unroll
  for (int q = 0; q < 4; q++) {
    f16x2 xa = {a[2 * q], a[2 * q + 1]};
    f16x2 xb = {b[2 * q], b[2 * q + 1]};
    acc = __builtin_amdgcn_fdot2(xa, xb, acc, false);
  }
#else
#pragma unroll
  for (int e = 0; e < 8; e++) acc = fmaf((float)a[e], (float)b[e], acc);
#endif
  return acc;
}

// Gate-interleaved row permutation (R1+-verified): frag row m of N-tile tl holds
// original gate row g*100 + (4*tl + q), g = m&3, q = m>>2.
// => D: lane holds gates (i,f,g,o) of k=4*tl+(lane>>4), batch lane&1 in regs 0..3.
__device__ __forceinline__ int jmap(int tl, int m) { return (m & 3) * 100 + 4 * tl + (m >> 2); }

// weight element fetchers over padded K layouts (0 in pad regions).
// Bias fused at K=101 (hi) / 102 (lo) against B=1.0 — f32-exact via hi/lo f16 pair.
// L1 K-layout: [0..99]=h1, [100]=x, [101]=b_hi, [102]=b_lo, [103..127]=0
__device__ __forceinline__ __fp16 w1e(const float* Whh1, const float* Wih1,
                                      const float* bih1, const float* bhh1, int j, int k) {
  if (k < 100) return (__fp16)Whh1[j * 100 + k];
  if (k == 100) return (__fp16)Wih1[j];
  if (k == 101 || k == 102) {
    float b = bih1[j] + bhh1[j];
    __fp16 hi = (__fp16)b;
    return (k == 101) ? hi : (__fp16)(b - (float)hi);
  }
  return (__fp16)0.0f;
}
// L2 K-layout: [0..99]=h1(t), [100]=0(x-slot junk), [101]=b_hi, [102]=b_lo,
//              [103..111]=0, [112..211]=h2(t-1), [212..223]=0
__device__ __forceinline__ __fp16 w2e(const float* Wih2, const float* Whh2,
                                      const float* bih2, const float* bhh2, int j, int k) {
  if (k < 100) return (__fp16)Wih2[j * 100 + k];
  if (k == 101 || k == 102) {
    float b = bih2[j] + bhh2[j];
    __fp16 hi = (__fp16)b;
    return (k == 101) ? hi : (__fp16)(b - (float)hi);
  }
  if (k >= 112 && k < 212) return (__fp16)Whh2[j * 100 + (k - 112)];
  return (__fp16)0.0f;
}

// A-operand fragment builders: lane row m=lane&15, K elems (lane>>4)*8+0..7 of K-tile kt
__device__ __forceinline__ f16x8 mka1(const float* Whh1, const float* Wih1,
                                      const float* bih1, const float* bhh1,
                                      int tl, int kt, int m, int kg) {
  int j = jmap(tl, m);
  f16x8 r;
#pragma unroll
  for (int e = 0; e < 8; e++) r[e] = w1e(Whh1, Wih1, bih1, bhh1, j, kt * 32 + kg * 8 + e);
  return r;
}
__device__ __forceinline__ f16x8 mka2(const float* Wih2, const float* Whh2,
                                      const float* bih2, const float* bhh2,
                                      int tl, int kt, int m, int kg) {
  int j = jmap(tl, m);
  f16x8 r;
#pragma unroll
  for (int e = 0; e < 8; e++) r[e] = w2e(Wih2, Whh2, bih2, bhh2, j, kt * 32 + kg * 8 + e);
  return r;
}

__global__ __launch_bounds__(BLOCK, 2) void lstm2_mfma(
    const float* __restrict__ input,  // [512,1000]
    const float* __restrict__ Wih1,   // [400,1]
    const float* __restrict__ Whh1,   // [400,100]
    const float* __restrict__ bih1,
    const float* __restrict__ bhh1,
    const float* __restrict__ Wih2,   // [400,100]
    const float* __restrict__ Whh2,   // [400,100]
    const float* __restrict__ bih2,
    const float* __restrict__ bhh2,
    const float* __restrict__ Wlin,   // [1,100]
    const float* __restrict__ blin,   // [1]
    const int* __restrict__ futp,
    float* __restrict__ out)          // [512, 1000+future]
{
  // parity double-buffered activation vectors (B-operand sources)
  __shared__ __align__(16) __fp16 H1X[2][NB][RSTR];  // h1 | x@100 | 1.0@101,102 | 0
  __shared__ __align__(16) __fp16 H2s[2][NB][RSTR];  // h2 | 0 pads
  __shared__ __align__(16) float  xrow[NB][T_IN];    // staged inputs (8 KB)

  const int tid = threadIdx.x;
  const int lane = tid & 63;
  const int wv = tid >> 6;
  const int b0 = blockIdx.x * NB;
  const int F = futp[0];
  const int TT = T_IN + F;

  // ---------------- init: stage + zero ----------------
  for (int i = tid; i < NB * T_IN; i += BLOCK) {
    int b = i / T_IN, tt = i % T_IN;
    xrow[b][tt] = input[(size_t)(b0 + b) * T_IN + tt];
  }
  if (tid < 320) { ((uint32_t*)H1X)[tid] = 0u; ((uint32_t*)H2s)[tid] = 0u; }

  const int n15 = lane & 15;
  const int kg = lane >> 4;         // K-chunk index 0..3
  const int bcol = lane & 1;        // batch for B-reads

  // ---- act geometry: lane activates ONE of its accumulator quads ----
  const int sel = lane & 15;
  const int cg  = sel >> 1;                       // col-group
  const int ab  = sel & 1;                        // batch
  const int aq  = lane >> 4;                      // q 0..3
  const int atl = (cg == 0) ? wv : (cg == 1) ? 8 + wv : (cg == 2) ? 16 + wv : 24;
  const int ak  = atl * 4 + aq;                   // k index this lane owns (0..99)
  const bool awr1 = (sel < 6) || (wv == 0 && sel < 8);   // L1 writers (wave0 owns tile 24)
  const bool awr2 = (sel < 6) || (wv == 1 && sel < 8);   // L2 writers (wave1 owns tile 24)
  float c1v = 0.0f, c2v = 0.0f;                   // per-lane cell states
  const float blin0 = blin[0];

  // ---- y/AR-fold constants: Wlin chunks (per-lane) + Wih1 gate-quad (per-lane) ----
  f16x8 wlinv[4];
#pragma unroll
  for (int i = 0; i < 4; i++) {
#pragma unroll
    for (int e = 0; e < 8; e++) {
      int k = i * 32 + kg * 8 + e;
      wlinv[i][e] = (__fp16)((k < HID) ? Wlin[k] : 0.f);
    }
  }
  f32x4 wih1q;
#pragma unroll
  for (int g = 0; g < 4; g++) wih1q[g] = Wih1[g * 100 + ak];

  // ---- register-resident weight fragments (A-operand), tiles {wv, 8+wv, 16+wv} ----
  f16x8 W1f0[4], W1f1[4], W1f2[4], W2f0[7], W2f1[7], W2f2[7];
#pragma unroll
  for (int kt = 0; kt < 4; kt++) {
    W1f0[kt] = mka1(Whh1, Wih1, bih1, bhh1, wv, kt, n15, kg);
    W1f1[kt] = mka1(Whh1, Wih1, bih1, bhh1, 8 + wv, kt, n15, kg);
    W1f2[kt] = mka1(Whh1, Wih1, bih1, bhh1, 16 + wv, kt, n15, kg);
  }
#pragma unroll
  for (int kt = 0; kt < 7; kt++) {
    W2f0[kt] = mka2(Wih2, Whh2, bih2, bhh2, wv, kt, n15, kg);
    W2f1[kt] = mka2(Wih2, Whh2, bih2, bhh2, 8 + wv, kt, n15, kg);
    W2f2[kt] = mka2(Wih2, Whh2, bih2, bhh2, 16 + wv, kt, n15, kg);
  }
  // tile-24 fragments: UNION Wt[7] — wv0 holds the L1 half (kt 0..3),
  // wv1 holds the L2 half (kt 0..6). Never both on one wave (-16 regs vs R7).
  f16x8 Wt[7];
#pragma unroll
  for (int kt = 0; kt < 7; kt++) Wt[kt] = ZH8;
  if (wv == 0) {
#pragma unroll
    for (int kt = 0; kt < 4; kt++) Wt[kt] = mka1(Whh1, Wih1, bih1, bhh1, 24, kt, n15, kg);
  }
  if (wv == 1) {
#pragma unroll
    for (int kt = 0; kt < 7; kt++) Wt[kt] = mka2(Wih2, Whh2, bih2, bhh2, 24, kt, n15, kg);
  }

  __syncthreads();
  // specials: bias-ones at K=101,102 (both parities/batches); x(0) into parity 1
  if (tid < 4) { H1X[tid >> 1][tid & 1][101] = (__fp16)1.0f; H1X[tid >> 1][tid & 1][102] = (__fp16)1.0f; }
  if (tid >= 4 && tid < 6) H1X[1][tid - 4][100] = (__fp16)xrow[tid - 4][0];
  __syncthreads();

  f16x8 bH1a[4], bH2[3], bl2m;
  f32x4 c0, c1, c2, d0, d1, d2;
  f32x4 e3 = Z4;                    // UNION tile-24 acc: c3 on wv0 / d3 on wv1 (-4 regs)
  const f32x4 zz = Z4;              // persistent zero C-operand

// ---- B-operand reads (L1 and L2 share H1X kts 0..3) ----
#define RD_H1A(P) { _Pragma("unroll") for (int kt_ = 0; kt_ < 4; kt_++) \
    bH1a[kt_] = *(const f16x8*)&H1X[P][bcol][kt_ * 32 + kg * 8]; }
#define RD_L2M(P) { f16x8 hm_ = *(const f16x8*)&H2s[P][bcol][(kg >= 2) ? ((kg - 2) * 8) : 0]; \
    bl2m = (kg >= 2) ? hm_ : bH1a[3]; }
#define RD_H2P(P) { _Pragma("unroll") for (int kt_ = 0; kt_ < 3; kt_++) \
    bH2[kt_] = *(const f16x8*)&H2s[P][bcol][16 + kt_ * 32 + kg * 8]; }

// ---- MFMA bursts (bias arrives via K=101/102; first MFMA uses zz as C) ----
#define MFMA_L2 { \
    d0 = MF(W2f0[0], bH1a[0], zz); d1 = MF(W2f1[0], bH1a[0], zz); d2 = MF(W2f2[0], bH1a[0], zz); \
    d0 = MF(W2f0[1], bH1a[1], d0); d1 = MF(W2f1[1], bH1a[1], d1); d2 = MF(W2f2[1], bH1a[1], d2); \
    d0 = MF(W2f0[2], bH1a[2], d0); d1 = MF(W2f1[2], bH1a[2], d1); d2 = MF(W2f2[2], bH1a[2], d2); \
    d0 = MF(W2f0[3], bl2m, d0);    d1 = MF(W2f1[3], bl2m, d1);    d2 = MF(W2f2[3], bl2m, d2); \
    d0 = MF(W2f0[4], bH2[0], d0);  d1 = MF(W2f1[4], bH2[0], d1);  d2 = MF(W2f2[4], bH2[0], d2); \
    d0 = MF(W2f0[5], bH2[1], d0);  d1 = MF(W2f1[5], bH2[1], d1);  d2 = MF(W2f2[5], bH2[1], d2); \
    d0 = MF(W2f0[6], bH2[2], d0);  d1 = MF(W2f1[6], bH2[2], d1);  d2 = MF(W2f2[6], bH2[2], d2); \
    if (wv == 1) { \
      e3 = MF(Wt[0], bH1a[0], zz); e3 = MF(Wt[1], bH1a[1], e3); e3 = MF(Wt[2], bH1a[2], e3); \
      e3 = MF(Wt[3], bl2m, e3); \
      e3 = MF(Wt[4], bH2[0], e3);  e3 = MF(Wt[5], bH2[1], e3);  e3 = MF(Wt[6], bH2[2], e3); } }

#define MFMA_L1 { \
    c0 = MF(W1f0[0], bH1a[0], zz); c1 = MF(W1f1[0], bH1a[0], zz); c2 = MF(W1f2[0], bH1a[0], zz); \
    c0 = MF(W1f0[1], bH1a[1], c0); c1 = MF(W1f1[1], bH1a[1], c1); c2 = MF(W1f2[1], bH1a[1], c2); \
    c0 = MF(W1f0[2], bH1a[2], c0); c1 = MF(W1f1[2], bH1a[2], c1); c2 = MF(W1f2[2], bH1a[2], c2); \
    c0 = MF(W1f0[3], bH1a[3], c0); c1 = MF(W1f1[3], bH1a[3], c1); c2 = MF(W1f2[3], bH1a[3], c2); \
    if (wv == 0) { \
      e3 = MF(Wt[0], bH1a[0], zz); e3 = MF(Wt[1], bH1a[1], e3); \
      e3 = MF(Wt[2], bH1a[2], e3); e3 = MF(Wt[3], bH1a[3], e3); } }

// ---- in-register activations (cg==3 lanes read e3; discarded unless awr* true) ----
#define ACT1_TF(W_) { \
    f32x4 qq = (cg == 0) ? c0 : (cg == 1) ? c1 : (cg == 2) ? c2 : e3; \
    float sf_ = sigm(qq[1]), si_ = sigm(qq[0]), tg_ = tanh_fast(qq[2]); \
    c1v = sf_ * c1v + si_ * tg_; \
    float h_ = sigm(qq[3]) * tanh_fast(c1v); \
    if (awr1) H1X[W_][ab][ak] = (__fp16)h_; }

#define ACT1_AR(W_, YV_) { \
    f32x4 qq = (cg == 0) ? c0 : (cg == 1) ? c1 : (cg == 2) ? c2 : e3; \
    qq[0] = fmaf(wih1q[0], (YV_), qq[0]); qq[1] = fmaf(wih1q[1], (YV_), qq[1]); \
    qq[2] = fmaf(wih1q[2], (YV_), qq[2]); qq[3] = fmaf(wih1q[3], (YV_), qq[3]); \
    float sf_ = sigm(qq[1]), si_ = sigm(qq[0]), tg_ = tanh_fast(qq[2]); \
    c1v = sf_ * c1v + si_ * tg_; \
    float h_ = sigm(qq[3]) * tanh_fast(c1v); \
    if (awr1) H1X[W_][ab][ak] = (__fp16)h_; }

#define ACT2(W_) { \
    f32x4 qq = (cg == 0) ? d0 : (cg == 1) ? d1 : (cg == 2) ? d2 : e3; \
    float sf_ = sigm(qq[1]), si_ = sigm(qq[0]), tg_ = tanh_fast(qq[2]); \
    c2v = sf_ * c2v + si_ * tg_; \
    float h_ = sigm(qq[3]) * tanh_fast(c2v); \
    if (awr2) H2s[W_][ab][ak] = (__fp16)h_; }

// TF y-output: wave 7 only — dot8 over f16 h2 (same math as AR fold), 4 reads + 2 shfl
#define YTF(tt, P_) { if (wv == 7) { \
    float s_ = 0.0f; \
    _Pragma("unroll") for (int i_ = 0; i_ < 4; i_++) { \
      f16x8 hh_ = *(const f16x8*)&H2s[P_][bcol][i_ * 32 + kg * 8]; \
      s_ = dot8(hh_, wlinv[i_], s_); } \
    s_ += __shfl_xor(s_, 16, 64); \
    s_ += __shfl_xor(s_, 32, 64); \
    if (lane < 2) out[(size_t)(b0 + lane) * TT + (tt)] = s_ + blin0; } }

  // ---------------- prologue: L1 gates(0) from parity 1 (zeros + x(0)) ----------------
  RD_H1A(1)
  MFMA_L1
  ACT1_TF(0)                                           // h1(0) -> H1X[0]
  if (tid >= 384 && tid < 386) H1X[0][tid - 384][100] = (__fp16)xrow[tid - 384][1];  // x(1)
  __syncthreads();

  // ====== teacher-forced fused: iter t does L2(t) + L1(t+1); ONE barrier/step ======
  for (int t = 0; t < T_IN - 1; t++) {
    const int p = t & 1, w = p ^ 1;
    RD_H1A(p) RD_L2M(p) RD_H2P(p)
    MFMA_L2
    ACT2(w)                                            // h2(t)
    MFMA_L1
    if (t > 0) YTF(t - 1, p)                           // y(t-1) from h2(t-1), off critical path
    if (tid >= 384 && tid < 386 && t + 2 < T_IN)
      H1X[w][tid - 384][100] = (__fp16)xrow[tid - 384][t + 2];  // x(t+2)
    ACT1_TF(w)                                         // h1(t+1)
    __syncthreads();
  }

  // ---- one-time AR patch: remove x-coefficient from L1 kt3 (x-slot is stale in AR) ----
  // all patches are per-wave registers -> no barrier needed
  if (kg == 0) {
    W1f0[3][4] = (__fp16)0.f; W1f1[3][4] = (__fp16)0.f; W1f2[3][4] = (__fp16)0.f;
    if (wv == 0) Wt[3][4] = (__fp16)0.f;
  }

  // ====== autoregressive: 2 barriers/step; y folded as rank-1 scalar (s = Wlin.h2) ======
  for (int t = T_IN - 1; t < TT; t++) {
    const int p = t & 1, w = p ^ 1;
    RD_H1A(p) RD_L2M(p) RD_H2P(p)
    MFMA_L2                                            // gates2(t)
    if (t == T_IN - 1) YTF(t - 1, p)                   // catch-up y(T_IN-2)
    ACT2(w)                                            // h2(t)
    MFMA_L1                                            // L1(t+1) recurrent part (h1(t) only)
    __syncthreads();                                   // B1: h2(t) visible
    float s_ = 0.f;
#pragma unroll
    for (int i_ = 0; i_ < 4; i_++) {                   // s = Wlin . h2(t)  (per-lane batch)
      f16x8 hh_ = *(const f16x8*)&H2s[w][bcol][i_ * 32 + kg * 8];
      s_ = dot8(hh_, wlinv[i_], s_);
    }
    s_ += __shfl_xor(s_, 16, 64);
    s_ += __shfl_xor(s_, 32, 64);
    const float yv = s_ + blin0;                       // y(t) = x(t+1)
    if (wv == 0 && lane < 2) out[(size_t)(b0 + lane) * TT + t] = yv;
    ACT1_AR(w, yv)                                     // h1(t+1), x-term added in-register
    __syncthreads();                                   // B2: h1(t+1) visible
  }
}

extern "C" void kernel_launch(void* const* d_in, const int* in_sizes, int n_in,
                              void* d_out, int out_size, void* d_ws, size_t ws_size,
                              hipStream_t stream) {
  const float* input = (const float*)d_in[0];
  const float* Wih1  = (const float*)d_in[1];
  const float* Whh1  = (const float*)d_in[2];
  const float* bih1  = (const float*)d_in[3];
  const float* bhh1  = (const float*)d_in[4];
  const float* Wih2  = (const float*)d_in[5];
  const float* Whh2  = (const float*)d_in[6];
  const float* bih2  = (const float*)d_in[7];
  const float* bhh2  = (const float*)d_in[8];
  const float* Wlin  = (const float*)d_in[9];
  const float* blin  = (const float*)d_in[10];
  const int*   futp  = (const int*)d_in[11];
  float* out = (float*)d_out;

  dim3 grid(B_TOTAL / NB);  // 256 blocks, 1 per CU
  dim3 block(BLOCK);
  hipLaunchKernelGGL(lstm2_mfma, grid, block, 0, stream,
                     input, Wih1, Whh1, bih1, bhh1, Wih2, Whh2, bih2, bhh2,
                     Wlin, blin, futp, out);
}

// Round 11
// 1442.275 us; speedup vs baseline: 1.2482x; 1.0566x over previous
//
#include <hip/hip_runtime.h>
#include <stdint.h>

// Problem constants
#define HID 100
#define B_TOTAL 512
#define T_IN 1000
#define NB 2
#define BLOCK 512   // 8 waves, 2 waves/SIMD (R4/R7 optimum)
#define RSTR 160    // f16 row stride (320 B): batch 1 lands 16 banks away

typedef __fp16 f16x8 __attribute__((ext_vector_type(8)));
typedef __fp16 f16x2 __attribute__((ext_vector_type(2)));
typedef float f32x4 __attribute__((ext_vector_type(4)));

#define MF(A, B, C) __builtin_amdgcn_mfma_f32_16x16x32_f16((A), (B), (C), 0, 0, 0)
#define Z4 ((f32x4){0.f, 0.f, 0.f, 0.f})
#define ZH8 ((f16x8){(__fp16)0.f,(__fp16)0.f,(__fp16)0.f,(__fp16)0.f,(__fp16)0.f,(__fp16)0.f,(__fp16)0.f,(__fp16)0.f})

// ---- fast activation math (verified: absmax unchanged) ----
#if __has_builtin(__builtin_amdgcn_exp2f)
#define EXP2F(x) __builtin_amdgcn_exp2f(x)
#else
#define EXP2F(x) exp2f(x)
#endif
#if __has_builtin(__builtin_amdgcn_rcpf)
#define RCPF(x) __builtin_amdgcn_rcpf(x)
#else
#define RCPF(x) (1.0f / (x))
#endif
#define LOG2E 1.44269504f
__device__ __forceinline__ float sigm(float x) { return RCPF(1.0f + EXP2F(-LOG2E * x)); }
__device__ __forceinline__ float tanh_fast(float x) {
  return 1.0f - 2.0f * RCPF(EXP2F((2.0f * LOG2E) * x) + 1.0f);
}

// 8-wide f16 dot accumulating into f32 (v_dot2_f32_f16 when available)
__device__ __forceinline__ float dot8(f16x8 a, f16x8 b, float acc) {
#if __has_builtin(__builtin_amdgcn_fdot2)
#pragma unroll
  for (int q = 0; q < 4; q++) {
    f16x2 xa = {a[2 * q], a[2 * q + 1]};
    f16x2 xb = {b[2 * q], b[2 * q + 1]};
    acc = __builtin_amdgcn_fdot2(xa, xb, acc, false);
  }
#else
#pragma unroll
  for (int e = 0; e < 8; e++) acc = fmaf((float)a[e], (float)b[e], acc);
#endif
  return acc;
}

// Gate-interleaved row permutation (R1+-verified): frag row m of N-tile tl holds
// original gate row g*100 + (4*tl + q), g = m&3, q = m>>2.
// => D: lane holds gates (i,f,g,o) of k=4*tl+(lane>>4), batch lane&1 in regs 0..3.
__device__ __forceinline__ int jmap(int tl, int m) { return (m & 3) * 100 + 4 * tl + (m >> 2); }

// weight element fetchers over padded K layouts (0 in pad regions).
// Bias fused at K=101 (hi) / 102 (lo) against B=1.0 — f32-exact via hi/lo f16 pair.
// L1 K-layout: [0..99]=h1, [100]=x, [101]=b_hi, [102]=b_lo, [103..127]=0
__device__ __forceinline__ __fp16 w1e(const float* Whh1, const float* Wih1,
                                      const float* bih1, const float* bhh1, int j, int k) {
  if (k < 100) return (__fp16)Whh1[j * 100 + k];
  if (k == 100) return (__fp16)Wih1[j];
  if (k == 101 || k == 102) {
    float b = bih1[j] + bhh1[j];
    __fp16 hi = (__fp16)b;
    return (k == 101) ? hi : (__fp16)(b - (float)hi);
  }
  return (__fp16)0.0f;
}
// L2 K-layout: [0..99]=h1(t), [100]=0(x-slot junk), [101]=b_hi, [102]=b_lo,
//              [103..111]=0, [112..211]=h2(t-1), [212..223]=0
__device__ __forceinline__ __fp16 w2e(const float* Wih2, const float* Whh2,
                                      const float* bih2, const float* bhh2, int j, int k) {
  if (k < 100) return (__fp16)Wih2[j * 100 + k];
  if (k == 101 || k == 102) {
    float b = bih2[j] + bhh2[j];
    __fp16 hi = (__fp16)b;
    return (k == 101) ? hi : (__fp16)(b - (float)hi);
  }
  if (k >= 112 && k < 212) return (__fp16)Whh2[j * 100 + (k - 112)];
  return (__fp16)0.0f;
}

// A-operand fragment builders: lane row m=lane&15, K elems (lane>>4)*8+0..7 of K-tile kt
__device__ __forceinline__ f16x8 mka1(const float* Whh1, const float* Wih1,
                                      const float* bih1, const float* bhh1,
                                      int tl, int kt, int m, int kg) {
  int j = jmap(tl, m);
  f16x8 r;
#pragma unroll
  for (int e = 0; e < 8; e++) r[e] = w1e(Whh1, Wih1, bih1, bhh1, j, kt * 32 + kg * 8 + e);
  return r;
}
__device__ __forceinline__ f16x8 mka2(const float* Wih2, const float* Whh2,
                                      const float* bih2, const float* bhh2,
                                      int tl, int kt, int m, int kg) {
  int j = jmap(tl, m);
  f16x8 r;
#pragma unroll
  for (int e = 0; e < 8; e++) r[e] = w2e(Wih2, Whh2, bih2, bhh2, j, kt * 32 + kg * 8 + e);
  return r;
}

__global__ __launch_bounds__(BLOCK, 2) void lstm2_mfma(
    const float* __restrict__ input,  // [512,1000]
    const float* __restrict__ Wih1,   // [400,1]
    const float* __restrict__ Whh1,   // [400,100]
    const float* __restrict__ bih1,
    const float* __restrict__ bhh1,
    const float* __restrict__ Wih2,   // [400,100]
    const float* __restrict__ Whh2,   // [400,100]
    const float* __restrict__ bih2,
    const float* __restrict__ bhh2,
    const float* __restrict__ Wlin,   // [1,100]
    const float* __restrict__ blin,   // [1]
    const int* __restrict__ futp,
    float* __restrict__ out)          // [512, 1000+future]
{
  // parity double-buffered activation vectors (B-operand sources)
  __shared__ __align__(16) __fp16 H1X[2][NB][RSTR];  // h1 | x@100 | 1.0@101,102 | 0
  __shared__ __align__(16) __fp16 H2s[2][NB][RSTR];  // h2 | 0 pads
  __shared__ __align__(16) float  xrow[NB][T_IN];    // staged inputs (8 KB)

  const int tid = threadIdx.x;
  const int lane = tid & 63;
  const int wv = tid >> 6;
  const int b0 = blockIdx.x * NB;
  const int F = futp[0];
  const int TT = T_IN + F;

  // ---------------- init: stage + zero ----------------
  for (int i = tid; i < NB * T_IN; i += BLOCK) {
    int b = i / T_IN, tt = i % T_IN;
    xrow[b][tt] = input[(size_t)(b0 + b) * T_IN + tt];
  }
  if (tid < 320) { ((uint32_t*)H1X)[tid] = 0u; ((uint32_t*)H2s)[tid] = 0u; }

  const int n15 = lane & 15;
  const int kg = lane >> 4;         // K-chunk index 0..3
  const int bcol = lane & 1;        // batch for B-reads

  // ---- act geometry: lane activates ONE of its accumulator quads ----
  const int sel = lane & 15;
  const int cg  = sel >> 1;                       // col-group
  const int ab  = sel & 1;                        // batch
  const int aq  = lane >> 4;                      // q 0..3
  const int atl = (cg == 0) ? wv : (cg == 1) ? 8 + wv : (cg == 2) ? 16 + wv : 24;
  const int ak  = atl * 4 + aq;                   // k index this lane owns (0..99)
  const bool awr1 = (sel < 6) || (wv == 0 && sel < 8);   // L1 writers (wave0 owns tile 24)
  const bool awr2 = (sel < 6) || (wv == 1 && sel < 8);   // L2 writers (wave1 owns tile 24)
  float c1v = 0.0f, c2v = 0.0f;                   // per-lane cell states
  const float blin0 = blin[0];

  // ---- y/AR-fold constants: Wlin chunks (per-lane) + Wih1 gate-quad (per-lane) ----
  f16x8 wlinv[4];
#pragma unroll
  for (int i = 0; i < 4; i++) {
#pragma unroll
    for (int e = 0; e < 8; e++) {
      int k = i * 32 + kg * 8 + e;
      wlinv[i][e] = (__fp16)((k < HID) ? Wlin[k] : 0.f);
    }
  }
  f32x4 wih1q;
#pragma unroll
  for (int g = 0; g < 4; g++) wih1q[g] = Wih1[g * 100 + ak];

  // ---- register-resident weight fragments (A-operand), tiles {wv, 8+wv, 16+wv} ----
  f16x8 W1f0[4], W1f1[4], W1f2[4], W2f0[7], W2f1[7], W2f2[7];
#pragma unroll
  for (int kt = 0; kt < 4; kt++) {
    W1f0[kt] = mka1(Whh1, Wih1, bih1, bhh1, wv, kt, n15, kg);
    W1f1[kt] = mka1(Whh1, Wih1, bih1, bhh1, 8 + wv, kt, n15, kg);
    W1f2[kt] = mka1(Whh1, Wih1, bih1, bhh1, 16 + wv, kt, n15, kg);
  }
#pragma unroll
  for (int kt = 0; kt < 7; kt++) {
    W2f0[kt] = mka2(Wih2, Whh2, bih2, bhh2, wv, kt, n15, kg);
    W2f1[kt] = mka2(Wih2, Whh2, bih2, bhh2, 8 + wv, kt, n15, kg);
    W2f2[kt] = mka2(Wih2, Whh2, bih2, bhh2, 16 + wv, kt, n15, kg);
  }
  // tile-24 fragments in REGISTERS: L1-half on wave 0, L2-half on wave 1 (R7-verified;
  // R10's union of these regressed — separate arrays let phases schedule independently)
  f16x8 W1T[4], W2T[7];
#pragma unroll
  for (int kt = 0; kt < 4; kt++) W1T[kt] = ZH8;
#pragma unroll
  for (int kt = 0; kt < 7; kt++) W2T[kt] = ZH8;
  if (wv == 0) {
#pragma unroll
    for (int kt = 0; kt < 4; kt++) W1T[kt] = mka1(Whh1, Wih1, bih1, bhh1, 24, kt, n15, kg);
  }
  if (wv == 1) {
#pragma unroll
    for (int kt = 0; kt < 7; kt++) W2T[kt] = mka2(Wih2, Whh2, bih2, bhh2, 24, kt, n15, kg);
  }

  __syncthreads();
  // specials: bias-ones at K=101,102 (both parities/batches); x(0) into parity 1
  if (tid < 4) { H1X[tid >> 1][tid & 1][101] = (__fp16)1.0f; H1X[tid >> 1][tid & 1][102] = (__fp16)1.0f; }
  if (tid >= 4 && tid < 6) H1X[1][tid - 4][100] = (__fp16)xrow[tid - 4][0];
  __syncthreads();

  f16x8 bH1a[4], bH2[3], bl2m;
  f32x4 c0, c1, c2, d0, d1, d2;
  f32x4 c3 = Z4, d3 = Z4;           // tile-24 accs (live only on waves 0/1)
  const f32x4 zz = Z4;              // persistent zero C-operand

// ---- B-operand reads (L1 and L2 share H1X kts 0..3) ----
#define RD_H1A(P) { _Pragma("unroll") for (int kt_ = 0; kt_ < 4; kt_++) \
    bH1a[kt_] = *(const f16x8*)&H1X[P][bcol][kt_ * 32 + kg * 8]; }
#define RD_L2M(P) { f16x8 hm_ = *(const f16x8*)&H2s[P][bcol][(kg >= 2) ? ((kg - 2) * 8) : 0]; \
    bl2m = (kg >= 2) ? hm_ : bH1a[3]; }
#define RD_H2P(P) { _Pragma("unroll") for (int kt_ = 0; kt_ < 3; kt_++) \
    bH2[kt_] = *(const f16x8*)&H2s[P][bcol][16 + kt_ * 32 + kg * 8]; }

// ---- MFMA bursts (bias arrives via K=101/102; first MFMA uses zz as C) ----
#define MFMA_L2 { \
    __builtin_amdgcn_s_setprio(1); \
    d0 = MF(W2f0[0], bH1a[0], zz); d1 = MF(W2f1[0], bH1a[0], zz); d2 = MF(W2f2[0], bH1a[0], zz); \
    d0 = MF(W2f0[1], bH1a[1], d0); d1 = MF(W2f1[1], bH1a[1], d1); d2 = MF(W2f2[1], bH1a[1], d2); \
    d0 = MF(W2f0[2], bH1a[2], d0); d1 = MF(W2f1[2], bH1a[2], d1); d2 = MF(W2f2[2], bH1a[2], d2); \
    d0 = MF(W2f0[3], bl2m, d0);    d1 = MF(W2f1[3], bl2m, d1);    d2 = MF(W2f2[3], bl2m, d2); \
    d0 = MF(W2f0[4], bH2[0], d0);  d1 = MF(W2f1[4], bH2[0], d1);  d2 = MF(W2f2[4], bH2[0], d2); \
    d0 = MF(W2f0[5], bH2[1], d0);  d1 = MF(W2f1[5], bH2[1], d1);  d2 = MF(W2f2[5], bH2[1], d2); \
    d0 = MF(W2f0[6], bH2[2], d0);  d1 = MF(W2f1[6], bH2[2], d1);  d2 = MF(W2f2[6], bH2[2], d2); \
    if (wv == 1) { \
      d3 = MF(W2T[0], bH1a[0], zz); d3 = MF(W2T[1], bH1a[1], d3); d3 = MF(W2T[2], bH1a[2], d3); \
      d3 = MF(W2T[3], bl2m, d3); \
      d3 = MF(W2T[4], bH2[0], d3);  d3 = MF(W2T[5], bH2[1], d3);  d3 = MF(W2T[6], bH2[2], d3); } \
    __builtin_amdgcn_s_setprio(0); }

#define MFMA_L1 { \
    __builtin_amdgcn_s_setprio(1); \
    c0 = MF(W1f0[0], bH1a[0], zz); c1 = MF(W1f1[0], bH1a[0], zz); c2 = MF(W1f2[0], bH1a[0], zz); \
    c0 = MF(W1f0[1], bH1a[1], c0); c1 = MF(W1f1[1], bH1a[1], c1); c2 = MF(W1f2[1], bH1a[1], c2); \
    c0 = MF(W1f0[2], bH1a[2], c0); c1 = MF(W1f1[2], bH1a[2], c1); c2 = MF(W1f2[2], bH1a[2], c2); \
    c0 = MF(W1f0[3], bH1a[3], c0); c1 = MF(W1f1[3], bH1a[3], c1); c2 = MF(W1f2[3], bH1a[3], c2); \
    if (wv == 0) { \
      c3 = MF(W1T[0], bH1a[0], zz); c3 = MF(W1T[1], bH1a[1], c3); \
      c3 = MF(W1T[2], bH1a[2], c3); c3 = MF(W1T[3], bH1a[3], c3); } \
    __builtin_amdgcn_s_setprio(0); }

// ---- in-register activations ----
#define ACT1_TF(W_) { \
    f32x4 qq = (cg == 0) ? c0 : (cg == 1) ? c1 : (cg == 2) ? c2 : c3; \
    float sf_ = sigm(qq[1]), si_ = sigm(qq[0]), tg_ = tanh_fast(qq[2]); \
    c1v = sf_ * c1v + si_ * tg_; \
    float h_ = sigm(qq[3]) * tanh_fast(c1v); \
    if (awr1) H1X[W_][ab][ak] = (__fp16)h_; }

#define ACT1_AR(W_, YV_) { \
    f32x4 qq = (cg == 0) ? c0 : (cg == 1) ? c1 : (cg == 2) ? c2 : c3; \
    qq[0] = fmaf(wih1q[0], (YV_), qq[0]); qq[1] = fmaf(wih1q[1], (YV_), qq[1]); \
    qq[2] = fmaf(wih1q[2], (YV_), qq[2]); qq[3] = fmaf(wih1q[3], (YV_), qq[3]); \
    float sf_ = sigm(qq[1]), si_ = sigm(qq[0]), tg_ = tanh_fast(qq[2]); \
    c1v = sf_ * c1v + si_ * tg_; \
    float h_ = sigm(qq[3]) * tanh_fast(c1v); \
    if (awr1) H1X[W_][ab][ak] = (__fp16)h_; }

#define ACT2(W_) { \
    f32x4 qq = (cg == 0) ? d0 : (cg == 1) ? d1 : (cg == 2) ? d2 : d3; \
    float sf_ = sigm(qq[1]), si_ = sigm(qq[0]), tg_ = tanh_fast(qq[2]); \
    c2v = sf_ * c2v + si_ * tg_; \
    float h_ = sigm(qq[3]) * tanh_fast(c2v); \
    if (awr2) H2s[W_][ab][ak] = (__fp16)h_; }

// TF y-output: wave 7 only — dot8 over f16 h2 (same math as AR fold), 4 reads + 2 shfl
#define YTF(tt, P_) { if (wv == 7) { \
    float s_ = 0.0f; \
    _Pragma("unroll") for (int i_ = 0; i_ < 4; i_++) { \
      f16x8 hh_ = *(const f16x8*)&H2s[P_][bcol][i_ * 32 + kg * 8]; \
      s_ = dot8(hh_, wlinv[i_], s_); } \
    s_ += __shfl_xor(s_, 16, 64); \
    s_ += __shfl_xor(s_, 32, 64); \
    if (lane < 2) out[(size_t)(b0 + lane) * TT + (tt)] = s_ + blin0; } }

// ---- one full TF step with compile-time parity (enables immediate LDS offsets) ----
#define TF_BODY(T_, P_, W_) { \
    RD_H1A(P_) RD_L2M(P_) RD_H2P(P_) \
    MFMA_L2 \
    ACT2(W_) \
    MFMA_L1 \
    if ((T_) > 0) YTF((T_) - 1, P_) \
    if (tid >= 384 && tid < 386 && (T_) + 2 < T_IN) \
      H1X[W_][tid - 384][100] = (__fp16)xrow[tid - 384][(T_) + 2]; \
    ACT1_TF(W_) \
    __syncthreads(); }

// ---- one full AR step with compile-time parity ----
#define AR_BODY(T_, P_, W_) { \
    RD_H1A(P_) RD_L2M(P_) RD_H2P(P_) \
    MFMA_L2 \
    if ((T_) == T_IN - 1) YTF((T_) - 1, P_) \
    ACT2(W_) \
    MFMA_L1 \
    __syncthreads(); \
    { float s_ = 0.f; \
      _Pragma("unroll") for (int i_ = 0; i_ < 4; i_++) { \
        f16x8 hh_ = *(const f16x8*)&H2s[W_][bcol][i_ * 32 + kg * 8]; \
        s_ = dot8(hh_, wlinv[i_], s_); } \
      s_ += __shfl_xor(s_, 16, 64); \
      s_ += __shfl_xor(s_, 32, 64); \
      const float yv = s_ + blin0; \
      if (wv == 0 && lane < 2) out[(size_t)(b0 + lane) * TT + (T_)] = yv; \
      ACT1_AR(W_, yv) } \
    __syncthreads(); }

  // ---------------- prologue: L1 gates(0) from parity 1 (zeros + x(0)) ----------------
  RD_H1A(1)
  MFMA_L1
  ACT1_TF(0)                                           // h1(0) -> H1X[0]
  if (tid >= 384 && tid < 386) H1X[0][tid - 384][100] = (__fp16)xrow[tid - 384][1];  // x(1)
  __syncthreads();

  // ====== teacher-forced fused, x2 unrolled: iter t does L2(t) + L1(t+1) ======
  int t = 0;
  for (; t + 1 < T_IN - 1; t += 2) {
    TF_BODY(t, 0, 1)
    TF_BODY(t + 1, 1, 0)
  }
  if (t < T_IN - 1) { TF_BODY(t, 0, 1) }               // tail (T_IN-1 = 999 is odd)

  // ---- one-time AR patch: remove x-coefficient from L1 kt3 (x-slot is stale in AR) ----
  if (kg == 0) {
    W1f0[3][4] = (__fp16)0.f; W1f1[3][4] = (__fp16)0.f; W1f2[3][4] = (__fp16)0.f;
    if (wv == 0) W1T[3][4] = (__fp16)0.f;
  }

  // ====== autoregressive, x2 unrolled: 2 barriers/step; y folded as rank-1 scalar ======
  // first AR step is t = T_IN-1 = 999 (odd) -> p=1,w=0
  int ta = T_IN - 1;
  for (; ta + 1 < TT; ta += 2) {
    AR_BODY(ta, 1, 0)
    AR_BODY(ta + 1, 0, 1)
  }
  if (ta < TT) { AR_BODY(ta, 1, 0) }
}

extern "C" void kernel_launch(void* const* d_in, const int* in_sizes, int n_in,
                              void* d_out, int out_size, void* d_ws, size_t ws_size,
                              hipStream_t stream) {
  const float* input = (const float*)d_in[0];
  const float* Wih1  = (const float*)d_in[1];
  const float* Whh1  = (const float*)d_in[2];
  const float* bih1  = (const float*)d_in[3];
  const float* bhh1  = (const float*)d_in[4];
  const float* Wih2  = (const float*)d_in[5];
  const float* Whh2  = (const float*)d_in[6];
  const float* bih2  = (const float*)d_in[7];
  const float* bhh2  = (const float*)d_in[8];
  const float* Wlin  = (const float*)d_in[9];
  const float* blin  = (const float*)d_in[10];
  const int*   futp  = (const int*)d_in[11];
  float* out = (float*)d_out;

  dim3 grid(B_TOTAL / NB);  // 256 blocks, 1 per CU
  dim3 block(BLOCK);
  hipLaunchKernelGGL(lstm2_mfma, grid, block, 0, stream,
                     input, Wih1, Whh1, bih1, bhh1, Wih2, Whh2, bih2, bhh2,
                     Wlin, blin, futp, out);
}